// Round 3
// baseline (4130.207 us; speedup 1.0000x reference)
//
#include <hip/hip_runtime.h>
#include <hip/hip_bf16.h>

#define NTH 512
#define NN 2048
#define GG 64
#define QSTEPS (NN / NTH)   // 4
#define NWAVES (NTH / 64)   // 8

__device__ __forceinline__ float iou_pair(float ax1, float ay1, float ax2, float ay2,
                                          float bx1, float by1, float bx2, float by2) {
    float w = fminf(ax2, bx2) - fmaxf(ax1, bx1) + 1.0f;
    float h = fminf(ay2, by2) - fmaxf(ay1, by1) + 1.0f;
    w = fmaxf(w, 0.0f);
    h = fmaxf(h, 0.0f);
    float ov = w * h;
    float aarea = (ax2 - ax1 + 1.0f) * (ay2 - ay1 + 1.0f);
    float barea = (bx2 - bx1 + 1.0f) * (by2 - by1 + 1.0f);
    return ov / (aarea + barea - ov);
}

__global__ __launch_bounds__(NTH) void nms_loss_kernel(const int* __restrict__ gt_inds,
                                                       const float* __restrict__ gt_boxes,
                                                       const float* __restrict__ props,
                                                       float* __restrict__ out_pp) {
    const int b = blockIdx.x;
    const int tid = threadIdx.x;
    const int lane = tid & 63;
    const int wid = tid >> 6;

    __shared__ float sx1[NN], sy1[NN], sx2[NN], sy2[NN], ssc[NN];
    __shared__ short sgt[NN];
    __shared__ float sgiou[GG][GG];
    __shared__ unsigned long long salive[NN / 64];
    __shared__ int srec[GG];
    __shared__ float swa_s[NWAVES];
    __shared__ int swa_i[NWAVES];
    __shared__ float swb_l[NWAVES];
    __shared__ int swb_c[NWAVES], swb_n[NWAVES];
    __shared__ int s_sel;
    __shared__ int s_poscnt;

    // ---- load proposals into LDS (SoA), f32 ----
    const float* pb = props + (size_t)b * NN * 5;
    const int* gb = gt_inds + (size_t)b * NN;
    for (int j = tid; j < NN; j += NTH) {
        sx1[j] = pb[j * 5 + 0];
        sy1[j] = pb[j * 5 + 1];
        sx2[j] = pb[j * 5 + 2];
        sy2[j] = pb[j * 5 + 3];
        ssc[j] = pb[j * 5 + 4];
        sgt[j] = (short)gb[j];
    }
    // ---- gt x gt IoU table ----
    const float* gtb = gt_boxes + (size_t)b * GG * 4;
    for (int e = tid; e < GG * GG; e += NTH) {
        int r = e >> 6, c = e & 63;
        sgiou[r][c] = iou_pair(gtb[r * 4 + 0], gtb[r * 4 + 1], gtb[r * 4 + 2], gtb[r * 4 + 3],
                               gtb[c * 4 + 0], gtb[c * 4 + 1], gtb[c * 4 + 2], gtb[c * 4 + 3]);
    }
    if (tid < GG) srec[tid] = -1;
    __syncthreads();

    // ---- alive bitmask (pos = gt_inds >= 0) ----
    if (tid < NN / 64) {
        unsigned long long w = 0ull;
        for (int bit = 0; bit < 64; ++bit) {
            if (sgt[tid * 64 + bit] >= 0) w |= (1ull << bit);
        }
        salive[tid] = w;
    }
    __syncthreads();
    if (tid == 0) {
        int pc = 0;
        for (int w = 0; w < NN / 64; ++w) pc += __popcll(salive[w]);
        s_poscnt = pc;
    }
    __syncthreads();

    // thread-0 private scan state
    float tpull = 0.0f, tpush = 0.0f;
    int pcnt = 0, qcnt = 0;
    int alive_cnt = s_poscnt;

    for (int iter = 0; iter < NN; ++iter) {
        // ---- phase A: argmax of score over alive (first-index tie-break) ----
        float bs = -1e30f;
        int bi = NN;
        #pragma unroll
        for (int q = 0; q < QSTEPS; ++q) {
            int j = q * NTH + tid;
            bool al = (salive[j >> 6] >> (j & 63)) & 1ull;
            float s = al ? ssc[j] : -1e30f;
            if (s > bs || (s == bs && j < bi)) { bs = s; bi = j; }
        }
        for (int off = 32; off > 0; off >>= 1) {
            float os = __shfl_down(bs, off);
            int oi = __shfl_down(bi, off);
            if (os > bs || (os == bs && oi < bi)) { bs = os; bi = oi; }
        }
        if (lane == 0) { swa_s[wid] = bs; swa_i[wid] = bi; }
        __syncthreads();  // (a)
        if (tid == 0) {
            float gs = -1e30f;
            int gi = NN;
            for (int w = 0; w < NWAVES; ++w) {
                float os = swa_s[w];
                int oi = swa_i[w];
                if (os > gs || (os == gs && oi < gi)) { gs = os; gi = oi; }
            }
            s_sel = (gs <= -1e29f) ? -1 : gi;
        }
        __syncthreads();  // (b)
        const int i = s_sel;
        if (i < 0) break;  // no alive proposals -> remaining scan steps are no-ops

        const int g = (int)sgt[i];
        const float ix1 = sx1[i], iy1 = sy1[i], ix2 = sx2[i], iy2 = sy2[i];

        // ---- phase B: IoU row, push terms, suppression ----
        int cnt = 0, nov = 0;
        float slj = 0.0f;
        #pragma unroll
        for (int q = 0; q < QSTEPS; ++q) {
            int j = q * NTH + tid;
            bool al = (((salive[j >> 6] >> (j & 63)) & 1ull) != 0ull) && (j != i);
            float row = 0.0f;
            if (al) row = iou_pair(ix1, iy1, ix2, iy2, sx1[j], sy1[j], sx2[j], sy2[j]);
            bool ovl = al && (row > 0.5f);
            int gj = ovl ? (int)sgt[j] : 0;
            bool fin = ovl && (gj != g) && (row > sgiou[g][gj]);
            if (fin) {
                cnt += 1;
                slj += -logf(1.0f + 0.5f - row) * ssc[j];
            }
            nov += ovl ? 1 : 0;
            // wave w at step q owns exactly alive word (q*8 + w): ballot-aligned, race-free
            unsigned long long kill = __ballot(ovl || (j == i));
            if (lane == 0 && kill) salive[(q * NTH + wid * 64) >> 6] &= ~kill;
        }
        for (int off = 32; off > 0; off >>= 1) {
            cnt += __shfl_down(cnt, off);
            nov += __shfl_down(nov, off);
            slj += __shfl_down(slj, off);
        }
        if (lane == 0) { swb_c[wid] = cnt; swb_n[wid] = nov; swb_l[wid] = slj; }
        __syncthreads();  // (c)
        if (tid == 0) {
            int tc = 0, tn = 0;
            float tl = 0.0f;
            for (int w = 0; w < NWAVES; ++w) { tc += swb_c[w]; tn += swb_n[w]; tl += swb_l[w]; }
            int recg = srec[g];
            bool has_rec = (recg >= 0);
            int rec_i = has_rec ? recg : 0;
            float miou = iou_pair(ix1, iy1, ix2, iy2, sx1[rec_i], sy1[rec_i], sx2[rec_i], sy2[rec_i]);
            miou = fmaxf(miou, 1e-6f);
            float pull = -logf(miou) * ssc[i];
            bool add = (alive_cnt > 1);  // remaining = any(alive_p)
            float push = (tc > 0) ? (tl / (float)tc) : 0.0f;
            if (add && has_rec) tpull += pull;
            if (add) tpush += push;
            if (has_rec) pcnt += 1;          // counted even when !add (matches reference)
            if (add) qcnt += tc;
            if (!has_rec) srec[g] = i;
            alive_cnt -= (1 + tn);
        }
        // next iteration's (a)/(b) barriers order thread-0 state vs. everyone else
    }

    if (tid == 0) {
        float valid = (s_poscnt > 1) ? 1.0f : 0.0f;
        float pull_loss = tpull / ((float)pcnt + 1e-6f) * valid;
        float push_loss = tpush / ((float)qcnt + 1e-6f) * valid;
        out_pp[b * 2 + 0] = push_loss;
        out_pp[b * 2 + 1] = pull_loss;
    }
}

__global__ void finalize_kernel(const float* __restrict__ pp, float* __restrict__ out, int B) {
    if (threadIdx.x == 0 && blockIdx.x == 0) {
        float ps = 0.0f, pl = 0.0f;
        for (int b = 0; b < B; ++b) {
            ps += pp[b * 2 + 0];
            pl += pp[b * 2 + 1];
        }
        float inv = 1.0f / (float)B;
        out[0] = ps * inv * 1.0f;  // push_loss * PUSH_W
        out[1] = pl * inv * 1.0f;  // pull_loss * PULL_W
    }
}

extern "C" void kernel_launch(void* const* d_in, const int* in_sizes, int n_in,
                              void* d_out, int out_size, void* d_ws, size_t ws_size,
                              hipStream_t stream) {
    // inputs: 0=gt_inds(B*N i32), 1=anchor_gt_inds(B*N i32),
    //         2=gt_bboxes(B*G*4 f32), 3=proposal_list(B*N*5 f32)
    const int B = in_sizes[0] / NN;
    const int* anchor_gt = (const int*)d_in[1];
    const float* gtb = (const float*)d_in[2];
    const float* props = (const float*)d_in[3];
    float* pp = (float*)d_ws;

    nms_loss_kernel<<<dim3(B), dim3(NTH), 0, stream>>>(anchor_gt, gtb, props, pp);
    finalize_kernel<<<dim3(1), dim3(64), 0, stream>>>(pp, (float*)d_out, B);
}

// Round 4
// 3079.014 us; speedup vs baseline: 1.3414x; 1.3414x over previous
//
#include <hip/hip_runtime.h>
#include <hip/hip_bf16.h>

#define NTH 256        // 4 waves: setup + bitonic sort; wave 0 runs the scan
#define NN 2048
#define GG 64
#define NW 32          // 32 alive-words of 64 entries

union SortSh {
    unsigned long long keys[NN];   // sort phase
    float giou[GG][GG];            // scan phase (keys dead after gather)
};

__device__ __forceinline__ float iou_pair(float ax1, float ay1, float ax2, float ay2,
                                          float bx1, float by1, float bx2, float by2) {
    float w = fminf(ax2, bx2) - fmaxf(ax1, bx1) + 1.0f;
    float h = fminf(ay2, by2) - fmaxf(ay1, by1) + 1.0f;
    w = fmaxf(w, 0.0f);
    h = fmaxf(h, 0.0f);
    float ov = w * h;
    float aarea = (ax2 - ax1 + 1.0f) * (ay2 - ay1 + 1.0f);
    float barea = (bx2 - bx1 + 1.0f) * (by2 - by1 + 1.0f);
    return ov / (aarea + barea - ov);
}

__global__ __launch_bounds__(NTH, 1) void nms_scan_kernel(const int* __restrict__ gt_inds,
                                                          const float* __restrict__ gt_boxes,
                                                          const float* __restrict__ props,
                                                          float* __restrict__ out_pp) {
    __shared__ float sx1[NN], sy1[NN], sx2[NN], sy2[NN], ssc[NN];
    __shared__ short sgt[NN];
    __shared__ SortSh u;
    __shared__ unsigned long long salive[NW];
    __shared__ float recbox[GG][4];

    const int b = blockIdx.x, tid = threadIdx.x;
    const float* pb = props + (size_t)b * NN * 5;
    const int* gbi = gt_inds + (size_t)b * NN;

    // ---- build sort keys: descending score, ties -> ascending original index ----
    for (int j = tid; j < NN; j += NTH) {
        unsigned int sb = __float_as_uint(pb[j * 5 + 4]);   // scores are >= 0 -> bits monotone
        u.keys[j] = ((unsigned long long)sb << 32) | (unsigned long long)(NN - 1 - j);
    }
    __syncthreads();
    // ---- bitonic sort, descending by key ----
    for (int k = 2; k <= NN; k <<= 1) {
        for (int jj = k >> 1; jj > 0; jj >>= 1) {
            for (int i = tid; i < NN; i += NTH) {
                int l = i ^ jj;
                if (l > i) {
                    unsigned long long a = u.keys[i], c = u.keys[l];
                    bool up = ((i & k) == 0);   // descending blocks
                    if (up ? (a < c) : (a > c)) { u.keys[i] = c; u.keys[l] = a; }
                }
            }
            __syncthreads();
        }
    }
    // ---- gather payload into sorted-order SoA ----
    for (int r = tid; r < NN; r += NTH) {
        int orig = (NN - 1) - (int)(u.keys[r] & 0xffffffffu);
        sx1[r] = pb[orig * 5 + 0];
        sy1[r] = pb[orig * 5 + 1];
        sx2[r] = pb[orig * 5 + 2];
        sy2[r] = pb[orig * 5 + 3];
        ssc[r] = pb[orig * 5 + 4];
        sgt[r] = (short)gbi[orig];
    }
    __syncthreads();   // keys dead after this point
    // ---- gt x gt IoU table (overwrites key storage) ----
    const float* gtb = gt_boxes + (size_t)b * GG * 4;
    for (int e = tid; e < GG * GG; e += NTH) {
        int r = e >> 6, c = e & 63;
        u.giou[r][c] = iou_pair(gtb[r * 4 + 0], gtb[r * 4 + 1], gtb[r * 4 + 2], gtb[r * 4 + 3],
                                gtb[c * 4 + 0], gtb[c * 4 + 1], gtb[c * 4 + 2], gtb[c * 4 + 3]);
    }
    __syncthreads();

    if (tid >= 64) return;   // waves 1..3 done; wave 0 scans barrier-free
    const int lane = tid;

    // ---- per-lane register-resident data: lane holds entry q*64+lane ----
    float rx1[NW], ry1[NW], rx2[NW], ry2[NW], rsc[NW];
    int rgt[NW];
    unsigned long long aliveR[NW];
    unsigned int summary = 0;
    int alive_cnt = 0;
    #pragma unroll
    for (int q = 0; q < NW; ++q) {
        int j = q * 64 + lane;
        rx1[q] = sx1[j]; ry1[q] = sy1[j]; rx2[q] = sx2[j]; ry2[q] = sy2[j];
        rsc[q] = ssc[j]; rgt[q] = (int)sgt[j];
        unsigned long long w = __ballot(rgt[q] >= 0);
        aliveR[q] = w;
        if (lane == 0) salive[q] = w;
        if (w) summary |= (1u << q);
        alive_cnt += __popcll(w);
    }
    const int poscnt = alive_cnt;
    unsigned long long recmask = 0ull;
    float tpull = 0.0f;      // wave-uniform
    float tpush_l = 0.0f;    // per-lane, reduced once at end
    int pcnt = 0, qcnt = 0;  // wave-uniform

    while (summary) {
        // ---- selection: first alive in sorted order ----
        int wq = __builtin_ctz(summary);
        unsigned long long w0 = salive[wq];
        int i = wq * 64 + __builtin_ctzll(w0);
        float ix1 = sx1[i], iy1 = sy1[i], ix2 = sx2[i], iy2 = sy2[i], isc = ssc[i];
        int g = (int)sgt[i];
        bool add = (alive_cnt > 1);            // any(alive minus i)
        bool has_rec = (recmask >> g) & 1ull;

        // ---- pull term (uniform) ----
        if (add && has_rec) {
            float miou = iou_pair(ix1, iy1, ix2, iy2,
                                  recbox[g][0], recbox[g][1], recbox[g][2], recbox[g][3]);
            tpull += -logf(fmaxf(miou, 1e-6f)) * isc;
        }
        if (!has_rec) {
            recmask |= (1ull << g);
            if (lane == 0) { recbox[g][0] = ix1; recbox[g][1] = iy1; recbox[g][2] = ix2; recbox[g][3] = iy2; }
        }
        pcnt += has_rec ? 1 : 0;               // counted even when !add (matches ref)

        // ---- suppression row + push terms ----
        int cnt = 0;                            // uniform (from ballots)
        float slj = 0.0f;                       // per-lane partial
        const float* giou_g = &u.giou[g][0];
        #pragma unroll
        for (int q = 0; q < NW; ++q) {
            if (aliveR[q] == 0ull) continue;    // uniform skip (incl. all words < wq)
            bool alv = (aliveR[q] >> lane) & 1ull;
            float iouv = iou_pair(ix1, iy1, ix2, iy2, rx1[q], ry1[q], rx2[q], ry2[q]);
            bool ovl = alv && (iouv > 0.5f);    // j==i: iou=1 -> included -> removes i
            unsigned long long kill = __ballot(ovl);
            if (kill) {                          // uniform branch; rare (overlaps sparse)
                int gj = rgt[q];
                bool fin = ovl && (gj != g) && (iouv > giou_g[gj]);
                unsigned long long finb = __ballot(fin);
                if (finb) {
                    cnt += __popcll(finb);
                    if (fin) slj += -logf(1.5f - iouv) * rsc[q];
                }
                unsigned long long na = aliveR[q] & ~kill;
                aliveR[q] = na;
                alive_cnt -= __popcll(kill);
                if (!na) summary &= ~(1u << q);
                if (lane == 0) salive[q] = na;
            }
        }
        if (add) {
            qcnt += cnt;
            if (cnt > 0) tpush_l += slj / (float)cnt;   // cnt uniform -> sums to slj_sum/cnt
        }
    }

    // ---- single end-of-scan reduction for push ----
    for (int off = 32; off > 0; off >>= 1) tpush_l += __shfl_xor(tpush_l, off);
    if (lane == 0) {
        float valid = (poscnt > 1) ? 1.0f : 0.0f;
        out_pp[b * 2 + 0] = tpush_l / ((float)qcnt + 1e-6f) * valid;   // push
        out_pp[b * 2 + 1] = tpull / ((float)pcnt + 1e-6f) * valid;     // pull
    }
}

__global__ void finalize_kernel(const float* __restrict__ pp, float* __restrict__ out, int B) {
    if (threadIdx.x == 0 && blockIdx.x == 0) {
        float ps = 0.0f, pl = 0.0f;
        for (int b = 0; b < B; ++b) {
            ps += pp[b * 2 + 0];
            pl += pp[b * 2 + 1];
        }
        float inv = 1.0f / (float)B;
        out[0] = ps * inv * 1.0f;  // push_loss * PUSH_W
        out[1] = pl * inv * 1.0f;  // pull_loss * PULL_W
    }
}

extern "C" void kernel_launch(void* const* d_in, const int* in_sizes, int n_in,
                              void* d_out, int out_size, void* d_ws, size_t ws_size,
                              hipStream_t stream) {
    // inputs: 0=gt_inds(B*N i32), 1=anchor_gt_inds(B*N i32),
    //         2=gt_bboxes(B*G*4 f32), 3=proposal_list(B*N*5 f32)
    const int B = in_sizes[0] / NN;
    const int* anchor_gt = (const int*)d_in[1];
    const float* gtb = (const float*)d_in[2];
    const float* props = (const float*)d_in[3];
    float* pp = (float*)d_ws;

    nms_scan_kernel<<<dim3(B), dim3(NTH), 0, stream>>>(anchor_gt, gtb, props, pp);
    finalize_kernel<<<dim3(1), dim3(64), 0, stream>>>(pp, (float*)d_out, B);
}

// Round 5
// 261.283 us; speedup vs baseline: 15.8074x; 11.7842x over previous
//
#include <hip/hip_runtime.h>
#include <hip/hip_bf16.h>

#define NN 2048
#define GG 64
#define CAP 64

typedef unsigned long long u64;
typedef unsigned short u16;

__device__ __forceinline__ float iou_pair(float ax1, float ay1, float ax2, float ay2,
                                          float bx1, float by1, float bx2, float by2) {
    float w = fminf(ax2, bx2) - fmaxf(ax1, bx1) + 1.0f;
    float h = fminf(ay2, by2) - fmaxf(ay1, by1) + 1.0f;
    w = fmaxf(w, 0.0f);
    h = fmaxf(h, 0.0f);
    float ov = w * h;
    float aarea = (ax2 - ax1 + 1.0f) * (ay2 - ay1 + 1.0f);
    float barea = (bx2 - bx1 + 1.0f) * (by2 - by1 + 1.0f);
    return ov / (aarea + barea - ov);
}

// ---------------- K1: per-image bitonic sort + gt_iou table + colcnt zero ----------------
__global__ __launch_bounds__(256) void sort_kernel(const int* __restrict__ gt_inds,
                                                   const float* __restrict__ gt_boxes,
                                                   const float* __restrict__ props,
                                                   float* __restrict__ sx1, float* __restrict__ sy1,
                                                   float* __restrict__ sx2, float* __restrict__ sy2,
                                                   float* __restrict__ ssc, int* __restrict__ sgt,
                                                   float* __restrict__ giou, int* __restrict__ colcnt) {
    __shared__ u64 keys[NN];
    const int im = blockIdx.x, tid = threadIdx.x;
    const float* pb = props + (size_t)im * NN * 5;
    const int* gbi = gt_inds + (size_t)im * NN;
    const int base = im * NN;
    for (int j = tid; j < NN; j += 256) {
        colcnt[base + j] = 0;
        unsigned int sb = __float_as_uint(pb[j * 5 + 4]);   // scores >= 0 -> bits monotone
        keys[j] = ((u64)sb << 32) | (u64)(NN - 1 - j);      // ties -> lower original index first
    }
    __syncthreads();
    for (int k = 2; k <= NN; k <<= 1) {
        for (int jj = k >> 1; jj > 0; jj >>= 1) {
            for (int i = tid; i < NN; i += 256) {
                int l = i ^ jj;
                if (l > i) {
                    u64 a = keys[i], c = keys[l];
                    bool up = ((i & k) == 0);               // descending
                    if (up ? (a < c) : (a > c)) { keys[i] = c; keys[l] = a; }
                }
            }
            __syncthreads();
        }
    }
    for (int r = tid; r < NN; r += 256) {
        int orig = (NN - 1) - (int)(keys[r] & 0xffffffffu);
        sx1[base + r] = pb[orig * 5 + 0];
        sy1[base + r] = pb[orig * 5 + 1];
        sx2[base + r] = pb[orig * 5 + 2];
        sy2[base + r] = pb[orig * 5 + 3];
        ssc[base + r] = pb[orig * 5 + 4];
        sgt[base + r] = gbi[orig];
    }
    const float* gtb = gt_boxes + (size_t)im * GG * 4;
    for (int e = tid; e < GG * GG; e += 256) {
        int r = e >> 6, c = e & 63;
        giou[im * GG * GG + e] = iou_pair(gtb[r * 4 + 0], gtb[r * 4 + 1], gtb[r * 4 + 2], gtb[r * 4 + 3],
                                          gtb[c * 4 + 0], gtb[c * 4 + 1], gtb[c * 4 + 2], gtb[c * 4 + 3]);
    }
}

// ---------------- K2: parallel pair phase -> earlier-overlapper CSR lists ----------------
// grid: B*64 blocks; block (im, rb) handles sorted rows [rb*32, rb*32+32)
__global__ __launch_bounds__(256) void pair_kernel(const float* __restrict__ sx1, const float* __restrict__ sy1,
                                                   const float* __restrict__ sx2, const float* __restrict__ sy2,
                                                   const int* __restrict__ sgt,
                                                   int* __restrict__ colcnt, u16* __restrict__ colent) {
    const int im = blockIdx.x >> 6, rb = blockIdx.x & 63, tid = threadIdx.x;
    const int base = im * NN;
    for (int r = 0; r < 32; ++r) {
        int i = rb * 32 + r;
        if (sgt[base + i] < 0) continue;
        float ix1 = sx1[base + i], iy1 = sy1[base + i];
        float ix2 = sx2[base + i], iy2 = sy2[base + i];
        for (int j = i + 1 + tid; j < NN; j += 256) {
            if (sgt[base + j] < 0) continue;
            float v = iou_pair(ix1, iy1, ix2, iy2,
                               sx1[base + j], sy1[base + j], sx2[base + j], sy2[base + j]);
            if (v > 0.5f) {
                int slot = atomicAdd(&colcnt[base + j], 1);
                if (slot < CAP) colent[(size_t)(base + j) * CAP + slot] = (u16)i;
            }
        }
    }
}

// ---------------- K3: per-image fixpoint + parallel attribution + reduction ----------------
__global__ __launch_bounds__(512) void scan_kernel(const float* __restrict__ sx1, const float* __restrict__ sy1,
                                                   const float* __restrict__ sx2, const float* __restrict__ sy2,
                                                   const float* __restrict__ ssc, const int* __restrict__ sgt,
                                                   const float* __restrict__ giou, const int* __restrict__ colcnt,
                                                   const u16* __restrict__ colent, float* __restrict__ out_pp) {
    __shared__ unsigned char st[NN];      // 0=unresolved, 1=kept, 2=killed
    __shared__ int cntA[NN];
    __shared__ float sumA[NN];
    __shared__ unsigned char hk[NN];      // "this kept box suppressed someone"
    __shared__ int firstk[GG];            // min sorted-index kept per gt
    __shared__ int s_unres, s_last, s_pos, s_qcnt, s_pcnt;
    __shared__ float s_tpush, s_tpull;
    const int im = blockIdx.x, tid = threadIdx.x;
    const int base = im * NN;

    if (tid == 0) { s_last = -1; s_pos = 0; s_qcnt = 0; s_pcnt = 0; s_tpush = 0.f; s_tpull = 0.f; }
    if (tid < GG) firstk[tid] = 0x7fffffff;
    int lpos = 0;
    for (int j = tid; j < NN; j += 512) {
        int g = sgt[base + j];
        st[j] = (g >= 0) ? 0 : 2;         // non-positive: dead from the start, excluded everywhere
        lpos += (g >= 0) ? 1 : 0;
        cntA[j] = 0; sumA[j] = 0.f; hk[j] = 0;
    }
    atomicAdd(&s_pos, lpos);
    __syncthreads();

    // ---- fixpoint: kept <=> no kept earlier overlapper; each round resolves >=1 box ----
    while (true) {
        if (tid == 0) s_unres = 0;
        __syncthreads();
        int lu = 0;
        for (int j = tid; j < NN; j += 512) {
            if (st[j] != 0) continue;
            int cc = colcnt[base + j]; if (cc > CAP) cc = CAP;
            const u16* lst = colent + (size_t)(base + j) * CAP;
            bool anyK = false, anyU = false;
            for (int e = 0; e < cc; ++e) {
                unsigned char s = st[lst[e]];
                anyK |= (s == 1);
                anyU |= (s == 0);
            }
            if (anyK) st[j] = 2;          // suppressed by a kept earlier overlapper
            else if (!anyU) st[j] = 1;    // all earlier overlappers killed -> kept
            else ++lu;
        }
        atomicAdd(&s_unres, lu);
        __syncthreads();
        if (s_unres == 0) break;
        __syncthreads();                  // protect s_unres reset next round
    }

    // ---- killer + attribution + lastkept + firstkept (one parallel pass) ----
    for (int j = tid; j < NN; j += 512) {
        int g = sgt[base + j];
        if (st[j] == 1) {
            atomicMax(&s_last, j);
            atomicMin(&firstk[g], j);
        } else if (g >= 0) {
            // killed positive: killer = min-index kept earlier overlapper
            int cc = colcnt[base + j]; if (cc > CAP) cc = CAP;
            const u16* lst = colent + (size_t)(base + j) * CAP;
            int ki = 0x7fffffff;
            for (int e = 0; e < cc; ++e) {
                int ii = lst[e];
                if (st[ii] == 1 && ii < ki) ki = ii;
            }
            if (ki == 0x7fffffff) continue;   // cannot happen for a killed positive
            hk[ki] = 1;
            float v = iou_pair(sx1[base + ki], sy1[base + ki], sx2[base + ki], sy2[base + ki],
                               sx1[base + j], sy1[base + j], sx2[base + j], sy2[base + j]);
            int gi = sgt[base + ki];
            if (g != gi && v > giou[im * GG * GG + gi * GG + g]) {
                atomicAdd(&cntA[ki], 1);
                atomicAdd(&sumA[ki], -logf(1.5f - v) * ssc[base + j]);
            }
        }
    }
    __syncthreads();

    // ---- final accumulation over kept selections (order-free) ----
    for (int i = tid; i < NN; i += 512) {
        if (st[i] != 1) continue;
        int g = sgt[base + i];
        bool add = (i != s_last) || (hk[i] != 0);   // any(alive_p) at this selection
        int c = cntA[i];
        bool hr = firstk[g] < i;                    // an earlier kept with same gt exists
        if (add && c > 0) atomicAdd(&s_tpush, sumA[i] / (float)c);
        if (add) atomicAdd(&s_qcnt, c);
        if (hr) atomicAdd(&s_pcnt, 1);              // counted even when !add (matches ref)
        if (add && hr) {
            int r = firstk[g];
            float v = iou_pair(sx1[base + i], sy1[base + i], sx2[base + i], sy2[base + i],
                               sx1[base + r], sy1[base + r], sx2[base + r], sy2[base + r]);
            atomicAdd(&s_tpull, -logf(fmaxf(v, 1e-6f)) * ssc[base + i]);
        }
    }
    __syncthreads();
    if (tid == 0) {
        float valid = (s_pos > 1) ? 1.0f : 0.0f;
        out_pp[im * 2 + 0] = s_tpush / ((float)s_qcnt + 1e-6f) * valid;  // push
        out_pp[im * 2 + 1] = s_tpull / ((float)s_pcnt + 1e-6f) * valid;  // pull
    }
}

__global__ void finalize_kernel(const float* __restrict__ pp, float* __restrict__ out, int B) {
    if (threadIdx.x == 0 && blockIdx.x == 0) {
        float ps = 0.0f, pl = 0.0f;
        for (int b = 0; b < B; ++b) {
            ps += pp[b * 2 + 0];
            pl += pp[b * 2 + 1];
        }
        float inv = 1.0f / (float)B;
        out[0] = ps * inv * 1.0f;  // push_loss * PUSH_W
        out[1] = pl * inv * 1.0f;  // pull_loss * PULL_W
    }
}

extern "C" void kernel_launch(void* const* d_in, const int* in_sizes, int n_in,
                              void* d_out, int out_size, void* d_ws, size_t ws_size,
                              hipStream_t stream) {
    // inputs: 0=gt_inds(B*N i32), 1=anchor_gt_inds(B*N i32),
    //         2=gt_bboxes(B*G*4 f32), 3=proposal_list(B*N*5 f32)
    const int B = in_sizes[0] / NN;
    const int* anchor_gt = (const int*)d_in[1];
    const float* gtb = (const float*)d_in[2];
    const float* props = (const float*)d_in[3];

    // ---- workspace layout (~1.35 MB for B=4) ----
    char* w = (char*)d_ws;
    float* sx1 = (float*)w;  w += (size_t)B * NN * 4;
    float* sy1 = (float*)w;  w += (size_t)B * NN * 4;
    float* sx2 = (float*)w;  w += (size_t)B * NN * 4;
    float* sy2 = (float*)w;  w += (size_t)B * NN * 4;
    float* ssc = (float*)w;  w += (size_t)B * NN * 4;
    int*   sgt = (int*)w;    w += (size_t)B * NN * 4;
    float* giou = (float*)w; w += (size_t)B * GG * GG * 4;
    int*   colcnt = (int*)w; w += (size_t)B * NN * 4;
    u16*   colent = (u16*)w; w += (size_t)B * NN * CAP * 2;
    float* pp = (float*)w;

    sort_kernel<<<dim3(B), dim3(256), 0, stream>>>(anchor_gt, gtb, props,
                                                   sx1, sy1, sx2, sy2, ssc, sgt, giou, colcnt);
    pair_kernel<<<dim3(B * 64), dim3(256), 0, stream>>>(sx1, sy1, sx2, sy2, sgt, colcnt, colent);
    scan_kernel<<<dim3(B), dim3(512), 0, stream>>>(sx1, sy1, sx2, sy2, ssc, sgt, giou, colcnt, colent, pp);
    finalize_kernel<<<dim3(1), dim3(64), 0, stream>>>(pp, (float*)d_out, B);
}

// Round 6
// 84.197 us; speedup vs baseline: 49.0543x; 3.1032x over previous
//
#include <hip/hip_runtime.h>
#include <hip/hip_bf16.h>

#define NN 2048
#define GG 64
#define CAP 64
#define TS 128
#define NT (NN / TS)                 // 16 tiles
#define NPAIR (NT * (NT + 1) / 2)    // 136 tile pairs

typedef unsigned long long u64;
typedef unsigned short u16;

__device__ __forceinline__ float iou4(float4 a, float4 b) {
    float w = fminf(a.z, b.z) - fmaxf(a.x, b.x) + 1.0f;
    float h = fminf(a.w, b.w) - fmaxf(a.y, b.y) + 1.0f;
    w = fmaxf(w, 0.0f);
    h = fmaxf(h, 0.0f);
    float ov = w * h;
    float aa = (a.z - a.x + 1.0f) * (a.w - a.y + 1.0f);
    float ab = (b.z - b.x + 1.0f) * (b.w - b.y + 1.0f);
    return ov / (aa + ab - ov);
}

__device__ __forceinline__ float wredf(float v) {
    for (int o = 32; o > 0; o >>= 1) v += __shfl_down(v, o);
    return v;
}
__device__ __forceinline__ int wredi(int v) {
    for (int o = 32; o > 0; o >>= 1) v += __shfl_down(v, o);
    return v;
}

// ---------------- K1: per-image bitonic sort + gt_iou table + colcnt zero ----------------
__global__ __launch_bounds__(1024) void sort_kernel(const int* __restrict__ gt_inds,
                                                    const float* __restrict__ gt_boxes,
                                                    const float* __restrict__ props,
                                                    float4* __restrict__ sbox, float* __restrict__ ssc,
                                                    int* __restrict__ sgt,
                                                    float* __restrict__ giou, int* __restrict__ colcnt) {
    __shared__ u64 keys[NN];
    const int im = blockIdx.x, tid = threadIdx.x;
    const float* pb = props + (size_t)im * NN * 5;
    const int* gbi = gt_inds + (size_t)im * NN;
    const int base = im * NN;
    for (int j = tid; j < NN; j += 1024) {
        colcnt[base + j] = 0;
        unsigned int sb = __float_as_uint(pb[j * 5 + 4]);   // scores >= 0 -> bits monotone
        keys[j] = ((u64)sb << 32) | (u64)(NN - 1 - j);      // ties -> lower original index first
    }
    __syncthreads();
    for (int k = 2; k <= NN; k <<= 1) {
        for (int jj = k >> 1; jj > 0; jj >>= 1) {
            for (int i = tid; i < NN; i += 1024) {
                int l = i ^ jj;
                if (l > i) {
                    u64 a = keys[i], c = keys[l];
                    bool up = ((i & k) == 0);               // descending
                    if (up ? (a < c) : (a > c)) { keys[i] = c; keys[l] = a; }
                }
            }
            __syncthreads();
        }
    }
    for (int r = tid; r < NN; r += 1024) {
        int orig = (NN - 1) - (int)(keys[r] & 0xffffffffu);
        sbox[base + r] = make_float4(pb[orig * 5 + 0], pb[orig * 5 + 1],
                                     pb[orig * 5 + 2], pb[orig * 5 + 3]);
        ssc[base + r] = pb[orig * 5 + 4];
        sgt[base + r] = gbi[orig];
    }
    const float* gtb = gt_boxes + (size_t)im * GG * 4;
    for (int e = tid; e < GG * GG; e += 1024) {
        int r = e >> 6, c = e & 63;
        float4 br = make_float4(gtb[r * 4 + 0], gtb[r * 4 + 1], gtb[r * 4 + 2], gtb[r * 4 + 3]);
        float4 bc = make_float4(gtb[c * 4 + 0], gtb[c * 4 + 1], gtb[c * 4 + 2], gtb[c * 4 + 3]);
        giou[im * GG * GG + e] = iou4(br, bc);
    }
}

// ---------------- K2: balanced LDS-tiled pair phase -> earlier-overlapper CSR ----------------
// grid: B*NPAIR blocks; block = (im, tile-pair a<=b). 256 threads.
__global__ __launch_bounds__(256) void pair_kernel(const float4* __restrict__ sbox,
                                                   const int* __restrict__ sgt,
                                                   int* __restrict__ colcnt, u16* __restrict__ colent) {
    const int im = blockIdx.x / NPAIR;
    int p = blockIdx.x % NPAIR;
    int a = 0;
    while (p >= NT - a) { p -= NT - a; ++a; }
    const int bt = a + p;
    const int base = im * NN;
    __shared__ float4 Abox[TS];
    __shared__ int Ag[TS];
    __shared__ float4 Bbox[TS];
    __shared__ int Bg[TS];
    const int tid = threadIdx.x;
    for (int t = tid; t < TS; t += 256) {
        Abox[t] = sbox[base + a * TS + t];
        Ag[t] = sgt[base + a * TS + t];
        Bbox[t] = sbox[base + bt * TS + t];
        Bg[t] = sgt[base + bt * TS + t];
    }
    __syncthreads();
    const int pr = tid & (TS - 1);      // row within tile a
    const int half = tid >> 7;          // 0/1: column half
    const float4 rb = Abox[pr];
    const int rg = Ag[pr];
    const int i = a * TS + pr;
    if (rg >= 0) {
        #pragma unroll 4
        for (int k = 0; k < TS / 2; ++k) {
            int jl = half * (TS / 2) + k;
            if (a == bt && jl <= pr) continue;   // need i < j
            if (Bg[jl] < 0) continue;
            float v = iou4(rb, Bbox[jl]);
            if (v > 0.5f) {
                int j = bt * TS + jl;
                int slot = atomicAdd(&colcnt[base + j], 1);
                if (slot < CAP) colent[(size_t)(base + j) * CAP + slot] = (u16)i;
            }
        }
    }
}

// ---------------- K3: per-image fixpoint + parallel attribution + reduction ----------------
__global__ __launch_bounds__(1024) void scan_kernel(const float4* __restrict__ sbox,
                                                    const float* __restrict__ ssc, const int* __restrict__ sgt,
                                                    const float* __restrict__ giou, const int* __restrict__ colcnt,
                                                    const u16* __restrict__ colent, float* __restrict__ out_pp) {
    __shared__ unsigned char st[NN];      // 0=unresolved, 1=kept, 2=killed
    __shared__ unsigned char hk[NN];      // "this kept box suppressed someone"
    __shared__ int ccL[NN];               // capped colcnt
    __shared__ int cntA[NN];
    __shared__ float sumA[NN];
    __shared__ int firstk[GG];            // min sorted-index kept per gt
    __shared__ int s_unres, s_last, s_pos, s_qcnt, s_pcnt;
    __shared__ float s_tpush, s_tpull;
    const int im = blockIdx.x, tid = threadIdx.x;
    const int lane = tid & 63;
    const int base = im * NN;

    if (tid == 0) { s_last = -1; s_pos = 0; s_qcnt = 0; s_pcnt = 0; s_tpush = 0.f; s_tpull = 0.f; }
    if (tid < GG) firstk[tid] = 0x7fffffff;
    int lpos = 0;
    for (int j = tid; j < NN; j += 1024) {
        int g = sgt[base + j];
        st[j] = (g >= 0) ? 0 : 2;         // non-positive: dead from the start
        lpos += (g >= 0) ? 1 : 0;
        int cc = colcnt[base + j];
        ccL[j] = (cc > CAP) ? CAP : cc;
        cntA[j] = 0; sumA[j] = 0.f; hk[j] = 0;
    }
    lpos = wredi(lpos);
    if (lane == 0 && lpos) atomicAdd(&s_pos, lpos);
    __syncthreads();

    // ---- fixpoint: kept <=> no kept earlier overlapper ----
    while (true) {
        if (tid == 0) s_unres = 0;
        __syncthreads();
        int lu = 0;
        for (int j = tid; j < NN; j += 1024) {
            if (st[j] != 0) continue;
            int cc = ccL[j];
            const u16* lst = colent + (size_t)(base + j) * CAP;
            bool anyK = false, anyU = false;
            for (int e = 0; e < cc; ++e) {
                unsigned char s = st[lst[e]];
                anyK |= (s == 1);
                anyU |= (s == 0);
            }
            if (anyK) st[j] = 2;
            else if (!anyU) st[j] = 1;
            else ++lu;
        }
        lu = wredi(lu);
        if (lane == 0 && lu) atomicAdd(&s_unres, lu);
        __syncthreads();
        if (s_unres == 0) break;
        __syncthreads();                  // protect s_unres reset next round
    }

    // ---- killer attribution + firstk + last-kept ----
    int llast = -1;
    for (int j = tid; j < NN; j += 1024) {
        int g = sgt[base + j];
        if (st[j] == 1) {
            if (j > llast) llast = j;
            atomicMin(&firstk[g], j);
        } else if (g >= 0) {
            int cc = ccL[j];
            const u16* lst = colent + (size_t)(base + j) * CAP;
            int ki = 0x7fffffff;
            for (int e = 0; e < cc; ++e) {
                int ii = lst[e];
                if (st[ii] == 1 && ii < ki) ki = ii;
            }
            if (ki == 0x7fffffff) continue;   // cannot happen for a killed positive
            hk[ki] = 1;                       // benign race: all write 1
            float v = iou4(sbox[base + ki], sbox[base + j]);
            int gi = sgt[base + ki];
            if (g != gi && v > giou[im * GG * GG + gi * GG + g]) {
                atomicAdd(&cntA[ki], 1);
                atomicAdd(&sumA[ki], -logf(1.5f - v) * ssc[base + j]);
            }
        }
    }
    for (int o = 32; o > 0; o >>= 1) llast = max(llast, __shfl_down(llast, o));
    if (lane == 0) atomicMax(&s_last, llast);
    __syncthreads();

    // ---- final accumulation over kept selections (order-free, per-thread partials) ----
    float ltpush = 0.f, ltpull = 0.f;
    int lqcnt = 0, lpcnt = 0;
    const int slast = s_last;
    for (int i = tid; i < NN; i += 1024) {
        if (st[i] != 1) continue;
        int g = sgt[base + i];
        bool add = (i != slast) || (hk[i] != 0);    // any(alive_p) at this selection
        int c = cntA[i];
        bool hr = firstk[g] < i;
        if (add && c > 0) ltpush += sumA[i] / (float)c;
        if (add) lqcnt += c;
        if (hr) ++lpcnt;                             // counted even when !add (matches ref)
        if (add && hr) {
            float v = iou4(sbox[base + i], sbox[base + firstk[g]]);
            ltpull += -logf(fmaxf(v, 1e-6f)) * ssc[base + i];
        }
    }
    ltpush = wredf(ltpush); ltpull = wredf(ltpull);
    lqcnt = wredi(lqcnt); lpcnt = wredi(lpcnt);
    if (lane == 0) {
        if (ltpush != 0.f) atomicAdd(&s_tpush, ltpush);
        if (ltpull != 0.f) atomicAdd(&s_tpull, ltpull);
        if (lqcnt) atomicAdd(&s_qcnt, lqcnt);
        if (lpcnt) atomicAdd(&s_pcnt, lpcnt);
    }
    __syncthreads();
    if (tid == 0) {
        float valid = (s_pos > 1) ? 1.0f : 0.0f;
        out_pp[im * 2 + 0] = s_tpush / ((float)s_qcnt + 1e-6f) * valid;  // push
        out_pp[im * 2 + 1] = s_tpull / ((float)s_pcnt + 1e-6f) * valid;  // pull
    }
}

__global__ void finalize_kernel(const float* __restrict__ pp, float* __restrict__ out, int B) {
    if (threadIdx.x == 0 && blockIdx.x == 0) {
        float ps = 0.0f, pl = 0.0f;
        for (int b = 0; b < B; ++b) {
            ps += pp[b * 2 + 0];
            pl += pp[b * 2 + 1];
        }
        float inv = 1.0f / (float)B;
        out[0] = ps * inv * 1.0f;  // push_loss * PUSH_W
        out[1] = pl * inv * 1.0f;  // pull_loss * PULL_W
    }
}

extern "C" void kernel_launch(void* const* d_in, const int* in_sizes, int n_in,
                              void* d_out, int out_size, void* d_ws, size_t ws_size,
                              hipStream_t stream) {
    // inputs: 0=gt_inds(B*N i32), 1=anchor_gt_inds(B*N i32),
    //         2=gt_bboxes(B*G*4 f32), 3=proposal_list(B*N*5 f32)
    const int B = in_sizes[0] / NN;
    const int* anchor_gt = (const int*)d_in[1];
    const float* gtb = (const float*)d_in[2];
    const float* props = (const float*)d_in[3];

    // ---- workspace layout (~1.4 MB for B=4) ----
    char* w = (char*)d_ws;
    float4* sbox = (float4*)w; w += (size_t)B * NN * 16;
    float* ssc = (float*)w;    w += (size_t)B * NN * 4;
    int*   sgt = (int*)w;      w += (size_t)B * NN * 4;
    float* giou = (float*)w;   w += (size_t)B * GG * GG * 4;
    int*   colcnt = (int*)w;   w += (size_t)B * NN * 4;
    u16*   colent = (u16*)w;   w += (size_t)B * NN * CAP * 2;
    float* pp = (float*)w;

    sort_kernel<<<dim3(B), dim3(1024), 0, stream>>>(anchor_gt, gtb, props,
                                                    sbox, ssc, sgt, giou, colcnt);
    pair_kernel<<<dim3(B * NPAIR), dim3(256), 0, stream>>>(sbox, sgt, colcnt, colent);
    scan_kernel<<<dim3(B), dim3(1024), 0, stream>>>(sbox, ssc, sgt, giou, colcnt, colent, pp);
    finalize_kernel<<<dim3(1), dim3(64), 0, stream>>>(pp, (float*)d_out, B);
}

// Round 7
// 61.040 us; speedup vs baseline: 67.6638x; 1.3794x over previous
//
#include <hip/hip_runtime.h>
#include <hip/hip_bf16.h>

#define NN 2048
#define GG 64
#define CAP 64
#define TS 128
#define NT (NN / TS)                 // 16 tiles
#define NPAIR (NT * (NT + 1) / 2)    // 136 tile pairs

typedef unsigned long long u64;
typedef unsigned short u16;

__device__ __forceinline__ float iou4(float4 a, float4 b) {
    float w = fminf(a.z, b.z) - fmaxf(a.x, b.x) + 1.0f;
    float h = fminf(a.w, b.w) - fmaxf(a.y, b.y) + 1.0f;
    w = fmaxf(w, 0.0f);
    h = fmaxf(h, 0.0f);
    float ov = w * h;
    float aa = (a.z - a.x + 1.0f) * (a.w - a.y + 1.0f);
    float ab = (b.z - b.x + 1.0f) * (b.w - b.y + 1.0f);
    return ov / (aa + ab - ov);
}

__device__ __forceinline__ float wredf(float v) {
    for (int o = 32; o > 0; o >>= 1) v += __shfl_down(v, o);
    return v;
}
__device__ __forceinline__ int wredi(int v) {
    for (int o = 32; o > 0; o >>= 1) v += __shfl_down(v, o);
    return v;
}

// key: larger = earlier in selection order (higher score; tie -> lower original idx)
__device__ __forceinline__ u64 make_key(float sc, int j) {
    return ((u64)__float_as_uint(sc) << 32) | (u64)(NN - 1 - j);
}

// ---------------- K0: pack boxes/keys, gt_iou table, zero colcnt + accumulators ----------------
__global__ __launch_bounds__(256) void prep_kernel(const int* __restrict__ gt_inds,
                                                   const float* __restrict__ gt_boxes,
                                                   const float* __restrict__ props,
                                                   float4* __restrict__ sbox, float* __restrict__ ssc,
                                                   u64* __restrict__ skey, int* __restrict__ sgt,
                                                   float* __restrict__ giou, int* __restrict__ colcnt,
                                                   float* __restrict__ acc, unsigned int* __restrict__ ctr) {
    const int im = blockIdx.x, tid = threadIdx.x;
    const float* pb = props + (size_t)im * NN * 5;
    const int* gbi = gt_inds + (size_t)im * NN;
    const int base = im * NN;
    for (int j = tid; j < NN; j += 256) {
        float x1 = pb[j * 5 + 0], y1 = pb[j * 5 + 1];
        float x2 = pb[j * 5 + 2], y2 = pb[j * 5 + 3];
        float sc = pb[j * 5 + 4];
        sbox[base + j] = make_float4(x1, y1, x2, y2);
        ssc[base + j] = sc;
        skey[base + j] = make_key(sc, j);
        sgt[base + j] = gbi[j];
        colcnt[base + j] = 0;
    }
    const float* gtb = gt_boxes + (size_t)im * GG * 4;
    for (int e = tid; e < GG * GG; e += 256) {
        int r = e >> 6, c = e & 63;
        float4 br = make_float4(gtb[r * 4 + 0], gtb[r * 4 + 1], gtb[r * 4 + 2], gtb[r * 4 + 3]);
        float4 bc = make_float4(gtb[c * 4 + 0], gtb[c * 4 + 1], gtb[c * 4 + 2], gtb[c * 4 + 3]);
        giou[im * GG * GG + e] = iou4(br, bc);
    }
    if (im == 0 && tid < 2) acc[tid] = 0.0f;
    if (im == 0 && tid == 0) *ctr = 0u;
}

// ---------------- K1: balanced LDS-tiled pair phase -> earlier-overlapper CSR ----------------
// grid: B*NPAIR blocks; block = (im, tile-pair a<=b) over ORIGINAL index order.
__global__ __launch_bounds__(256) void pair_kernel(const float4* __restrict__ sbox,
                                                   const u64* __restrict__ skey,
                                                   const int* __restrict__ sgt,
                                                   int* __restrict__ colcnt, u16* __restrict__ colent) {
    const int im = blockIdx.x / NPAIR;
    int p = blockIdx.x % NPAIR;
    int a = 0;
    while (p >= NT - a) { p -= NT - a; ++a; }
    const int bt = a + p;
    const int base = im * NN;
    __shared__ float4 Abox[TS], Bbox[TS];
    __shared__ u64 Akey[TS], Bkey[TS];
    __shared__ int Ag[TS], Bg[TS];
    const int tid = threadIdx.x;
    for (int t = tid; t < TS; t += 256) {
        Abox[t] = sbox[base + a * TS + t];
        Akey[t] = skey[base + a * TS + t];
        Ag[t] = sgt[base + a * TS + t];
        Bbox[t] = sbox[base + bt * TS + t];
        Bkey[t] = skey[base + bt * TS + t];
        Bg[t] = sgt[base + bt * TS + t];
    }
    __syncthreads();
    const int pr = tid & (TS - 1);      // row within tile a
    const int half = tid >> 7;          // 0/1: column half within tile bt
    const float4 rb = Abox[pr];
    const u64 rk = Akey[pr];
    const int i = a * TS + pr;
    if (Ag[pr] >= 0) {
        #pragma unroll 4
        for (int k = 0; k < TS / 2; ++k) {
            int jl = half * (TS / 2) + k;
            if (a == bt && jl <= pr) continue;   // unordered pairs once
            if (Bg[jl] < 0) continue;
            float v = iou4(rb, Bbox[jl]);
            if (v > 0.5f) {
                int j = bt * TS + jl;
                // record the EARLIER (larger key) into the LATER's list
                int late, early;
                if (rk > Bkey[jl]) { late = j; early = i; }
                else               { late = i; early = j; }
                int slot = atomicAdd(&colcnt[base + late], 1);
                if (slot < CAP) colent[(size_t)(base + late) * CAP + slot] = (u16)early;
            }
        }
    }
}

// ---------------- K2: per-image fixpoint + attribution + reduction + fused finalize ----------------
__global__ __launch_bounds__(1024) void scan_kernel(const float4* __restrict__ sbox,
                                                    const float* __restrict__ ssc, const int* __restrict__ sgt,
                                                    const u64* __restrict__ skey,
                                                    const float* __restrict__ giou, const int* __restrict__ colcnt,
                                                    const u16* __restrict__ colent,
                                                    float* __restrict__ acc, unsigned int* __restrict__ ctr,
                                                    float* __restrict__ out, int B) {
    __shared__ unsigned char st[NN];      // 0=unresolved, 1=kept, 2=killed
    __shared__ unsigned char hk[NN];      // kept box suppressed someone
    __shared__ unsigned char ccL[NN];     // capped list length
    __shared__ u64 keyL[NN];
    __shared__ int cntA[NN];
    __shared__ float sumA[NN];
    __shared__ u64 firstk[GG];            // max key among kept per gt (0 = none)
    __shared__ u64 s_minkey;              // min key among kept
    __shared__ int s_unres, s_pos, s_qcnt, s_pcnt;
    __shared__ float s_tpush, s_tpull;
    const int im = blockIdx.x, tid = threadIdx.x;
    const int lane = tid & 63;
    const int base = im * NN;

    if (tid == 0) { s_pos = 0; s_qcnt = 0; s_pcnt = 0; s_tpush = 0.f; s_tpull = 0.f; s_minkey = ~0ull; }
    if (tid < GG) firstk[tid] = 0ull;
    int lpos = 0;
    for (int j = tid; j < NN; j += 1024) {
        int g = sgt[base + j];
        st[j] = (g >= 0) ? 0 : 2;
        lpos += (g >= 0) ? 1 : 0;
        int cc = colcnt[base + j];
        ccL[j] = (unsigned char)((cc > CAP) ? CAP : cc);
        keyL[j] = skey[base + j];
        cntA[j] = 0; sumA[j] = 0.f; hk[j] = 0;
    }
    lpos = wredi(lpos);
    if (lane == 0 && lpos) atomicAdd(&s_pos, lpos);
    __syncthreads();

    // ---- fixpoint: kept <=> no kept earlier overlapper ----
    while (true) {
        if (tid == 0) s_unres = 0;
        __syncthreads();
        int lu = 0;
        for (int j = tid; j < NN; j += 1024) {
            if (st[j] != 0) continue;
            int cc = ccL[j];
            const u16* lst = colent + (size_t)(base + j) * CAP;
            bool anyK = false, anyU = false;
            for (int e = 0; e < cc; ++e) {
                unsigned char s = st[lst[e]];
                anyK |= (s == 1);
                anyU |= (s == 0);
            }
            if (anyK) st[j] = 2;
            else if (!anyU) st[j] = 1;
            else ++lu;
        }
        lu = wredi(lu);
        if (lane == 0 && lu) atomicAdd(&s_unres, lu);
        __syncthreads();
        if (s_unres == 0) break;
        __syncthreads();                  // protect s_unres reset next round
    }

    // ---- pass 1: kept bookkeeping + killer attribution ----
    for (int j = tid; j < NN; j += 1024) {
        int g = sgt[base + j];
        if (st[j] == 1) {
            atomicMin(&s_minkey, keyL[j]);
            atomicMax(&firstk[g], keyL[j]);
        } else if (g >= 0) {
            int cc = ccL[j];
            const u16* lst = colent + (size_t)(base + j) * CAP;
            u64 bk = 0ull; int ki = -1;
            for (int e = 0; e < cc; ++e) {
                int ii = lst[e];
                if (st[ii] == 1 && keyL[ii] > bk) { bk = keyL[ii]; ki = ii; }
            }
            if (ki < 0) continue;             // cannot happen for a killed positive
            hk[ki] = 1;                       // benign race: all write 1
            float v = iou4(sbox[base + ki], sbox[base + j]);
            int gi = sgt[base + ki];
            if (g != gi && v > giou[im * GG * GG + gi * GG + g]) {
                atomicAdd(&cntA[ki], 1);
                atomicAdd(&sumA[ki], -logf(1.5f - v) * ssc[base + j]);
            }
        }
    }
    __syncthreads();

    // ---- pass 2: accumulation over kept selections (order-free) ----
    float ltpush = 0.f, ltpull = 0.f;
    int lqcnt = 0, lpcnt = 0;
    const u64 minkey = s_minkey;
    for (int i = tid; i < NN; i += 1024) {
        if (st[i] != 1) continue;
        int g = sgt[base + i];
        u64 fk = firstk[g];
        bool add = (keyL[i] != minkey) || (hk[i] != 0);   // any(alive_p) at this selection
        int c = cntA[i];
        bool hr = fk > keyL[i];                            // earlier kept with same gt
        if (add && c > 0) ltpush += sumA[i] / (float)c;
        if (add) lqcnt += c;
        if (hr) ++lpcnt;                                   // counted even when !add (matches ref)
        if (add && hr) {
            int r = (NN - 1) - (int)(fk & 0xffffffffu);
            float v = iou4(sbox[base + i], sbox[base + r]);
            ltpull += -logf(fmaxf(v, 1e-6f)) * ssc[base + i];
        }
    }
    ltpush = wredf(ltpush); ltpull = wredf(ltpull);
    lqcnt = wredi(lqcnt); lpcnt = wredi(lpcnt);
    if (lane == 0) {
        if (ltpush != 0.f) atomicAdd(&s_tpush, ltpush);
        if (ltpull != 0.f) atomicAdd(&s_tpull, ltpull);
        if (lqcnt) atomicAdd(&s_qcnt, lqcnt);
        if (lpcnt) atomicAdd(&s_pcnt, lpcnt);
    }
    __syncthreads();

    // ---- fused finalize: last-finishing block computes the B-mean ----
    if (tid == 0) {
        float valid = (s_pos > 1) ? 1.0f : 0.0f;
        float push_b = s_tpush / ((float)s_qcnt + 1e-6f) * valid;
        float pull_b = s_tpull / ((float)s_pcnt + 1e-6f) * valid;
        atomicAdd(&acc[0], push_b);
        atomicAdd(&acc[1], pull_b);
        __threadfence();
        unsigned int old = atomicAdd(ctr, 1u);
        if (old == (unsigned int)(B - 1)) {
            float ps = atomicAdd(&acc[0], 0.0f);   // coherent device-scope read
            float pl = atomicAdd(&acc[1], 0.0f);
            float inv = 1.0f / (float)B;
            out[0] = ps * inv * 1.0f;  // push_loss * PUSH_W
            out[1] = pl * inv * 1.0f;  // pull_loss * PULL_W
        }
    }
}

extern "C" void kernel_launch(void* const* d_in, const int* in_sizes, int n_in,
                              void* d_out, int out_size, void* d_ws, size_t ws_size,
                              hipStream_t stream) {
    // inputs: 0=gt_inds(B*N i32), 1=anchor_gt_inds(B*N i32),
    //         2=gt_bboxes(B*G*4 f32), 3=proposal_list(B*N*5 f32)
    const int B = in_sizes[0] / NN;
    const int* anchor_gt = (const int*)d_in[1];
    const float* gtb = (const float*)d_in[2];
    const float* props = (const float*)d_in[3];

    // ---- workspace layout (alignment-ordered, ~1.4 MB for B=4) ----
    char* w = (char*)d_ws;
    float4* sbox = (float4*)w;   w += (size_t)B * NN * 16;
    u64*    skey = (u64*)w;      w += (size_t)B * NN * 8;
    float*  giou = (float*)w;    w += (size_t)B * GG * GG * 4;
    float*  ssc = (float*)w;     w += (size_t)B * NN * 4;
    int*    sgt = (int*)w;       w += (size_t)B * NN * 4;
    int*    colcnt = (int*)w;    w += (size_t)B * NN * 4;
    float*  acc = (float*)w;     w += 8;
    unsigned int* ctr = (unsigned int*)w; w += 8;
    u16*    colent = (u16*)w;

    prep_kernel<<<dim3(B), dim3(256), 0, stream>>>(anchor_gt, gtb, props,
                                                   sbox, ssc, skey, sgt, giou, colcnt, acc, ctr);
    pair_kernel<<<dim3(B * NPAIR), dim3(256), 0, stream>>>(sbox, skey, sgt, colcnt, colent);
    scan_kernel<<<dim3(B), dim3(1024), 0, stream>>>(sbox, ssc, sgt, skey, giou, colcnt, colent,
                                                    acc, ctr, (float*)d_out, B);
}